// Round 24
// baseline (41.499 us; speedup 1.0000x reference)
//
#include <hip/hip_runtime.h>

#define WI 4096
#define HI 4096
#define WO 4090
#define HO 4090
#define TH 16              // output rows per tile
#define IH 22              // staged input rows per tile (TH + 6)
#define LW 536             // bf16 per LDS row: covers max READ footprint 528
#define CPR4 134           // float4 chunks per row (LW/4)
#define NCHK (IH*CPR4)     // 2948 chunks per tile

typedef __attribute__((ext_vector_type(8))) short bf16x8;
typedef __attribute__((ext_vector_type(4))) float f32x4;

__device__ __forceinline__ unsigned short f2bf(float f) {
    union { float f; unsigned u; } v; v.f = f;
    unsigned r = v.u + 0x7FFFu + ((v.u >> 16) & 1u);   // RNE
    return (unsigned short)(r >> 16);
}

__global__ __launch_bounds__(256, 4) void conv7x7(
    const float* __restrict__ x, const float* __restrict__ wgt,
    const float* __restrict__ bias, float* __restrict__ out)
{
    __shared__ unsigned short tile[IH * LW];   // 23,584 B (single buffer)

    const int tid = threadIdx.x;
    const int x0  = blockIdx.x * 512;          // aligned 512-wide stripes
    const int y0b = blockIdx.y * 32;           // two 16-row tiles per block
    const float bb = bias[0];

    // ---- banded B fragments (uniform s_load weights, built once) ----
    // B_ky[k][n] = W[ky][k-n] for 0 <= k-n < 7 else 0
    const int n   = tid & 15;                // lane&15
    const int kb8 = ((tid >> 4) & 3) << 3;   // k-block base (lane>>4)*8
    bf16x8 Bf[7];
    #pragma unroll
    for (int ky = 0; ky < 7; ++ky) {
        #pragma unroll
        for (int j = 0; j < 8; ++j) {
            const int t = kb8 + j - n;
            const float wv = (t >= 0 && t < 7) ? wgt[ky * 7 + t] : 0.f;
            Bf[ky][j] = (short)f2bf(wv);
        }
    }

    // ---- helpers ----
    auto issue_loads = [&](int y0, float4* qv) {
        #pragma unroll
        for (int k = 0; k < 12; ++k) {
            const int c = tid + (k << 8);
            const int row = c / CPR4;              // magic-mul div
            const int c4  = c - row * CPR4;
            const int rowc = (c < NCHK) ? row : (IH - 1);
            int gy  = y0 + rowc;      gy  = gy  < HI ? gy : HI - 1;
            int gxs = x0 + (c4 << 2); gxs = gxs <= WI - 4 ? gxs : WI - 4;
            qv[k] = *(const float4*)(x + (size_t)gy * WI + gxs);
        }
    };
    auto cvt_store = [&](const float4* qv) {
        #pragma unroll
        for (int k = 0; k < 12; ++k) {
            const int c = tid + (k << 8);
            if (c < NCHK) {
                const int row = c / CPR4;
                const int c4  = c - row * CPR4;
                unsigned u0 = (unsigned)f2bf(qv[k].x) | ((unsigned)f2bf(qv[k].y) << 16);
                unsigned u1 = (unsigned)f2bf(qv[k].z) | ((unsigned)f2bf(qv[k].w) << 16);
                *(uint2*)&tile[row * LW + (c4 << 2)] = make_uint2(u0, u1);
            }
        }
    };
    auto compute = [&](int y0) {
        const int wcol  = (tid >> 6) << 7;                 // 0/128/256/384
        const int growb = y0 + (((tid >> 4) & 3) << 2);    // D row base
        #pragma unroll
        for (int tp = 0; tp < 4; ++tp) {
            const int xt0 = wcol + (tp << 5);
            const int xt1 = xt0 + 16;
            f32x4 acc0 = {0.f, 0.f, 0.f, 0.f};
            f32x4 acc1 = {0.f, 0.f, 0.f, 0.f};
            #pragma unroll
            for (int ky = 0; ky < 7; ++ky) {
                const unsigned short* rp = &tile[(ky + n) * LW + kb8];
                const bf16x8 av0 = *(const bf16x8*)(rp + xt0);   // 16B aligned
                const bf16x8 av1 = *(const bf16x8*)(rp + xt1);
                acc0 = __builtin_amdgcn_mfma_f32_16x16x32_bf16(av0, Bf[ky], acc0, 0, 0, 0);
                acc1 = __builtin_amdgcn_mfma_f32_16x16x32_bf16(av1, Bf[ky], acc1, 0, 0, 0);
            }
            const int gc0 = x0 + xt0 + n;
            const int gc1 = gc0 + 16;
            #pragma unroll
            for (int v = 0; v < 4; ++v) {
                const int grow = growb + v;
                if (grow < HO) {
                    if (gc0 < WO) out[(size_t)grow * WO + gc0] = acc0[v] + bb;
                    if (gc1 < WO) out[(size_t)grow * WO + gc1] = acc1[v] + bb;
                }
            }
        }
    };

    // ---- two-tile pipeline ----
    float4 qa[12];
    issue_loads(y0b, qa);
    cvt_store(qa);
    __syncthreads();                 // tile0 LDS ready

    float4 qb[12];
    issue_loads(y0b + TH, qb);       // in flight during compute(tile0)
    compute(y0b);                    // ~1500 cyc: hides tile1 HBM latency
    __syncthreads();                 // all waves done READING tile0 LDS

    cvt_store(qb);                   // overwrite LDS with tile1 (loads aged)
    __syncthreads();                 // tile1 LDS ready
    compute(y0b + TH);
}

extern "C" void kernel_launch(void* const* d_in, const int* in_sizes, int n_in,
                              void* d_out, int out_size, void* d_ws, size_t ws_size,
                              hipStream_t stream) {
    const float* x = (const float*)d_in[0];
    const float* w = (const float*)d_in[1];
    const float* b = (const float*)d_in[2];
    float* out = (float*)d_out;
    // 8 stripes x 512 cols; 128 y-blocks x 32 rows = 4096 >= 4090.
    // 1024 blocks = 4/CU = exactly one residency generation (no tail).
    dim3 grid(8, 128);
    conv7x7<<<grid, 256, 0, stream>>>(x, w, b, out);
}

// Round 25
// 29.997 us; speedup vs baseline: 1.3835x; 1.3835x over previous
//
#include <hip/hip_runtime.h>

#define WI 4096
#define HI 4096
#define WO 4090
#define HO 4090
#define TH 16              // output rows per block
#define IH 22              // staged input rows (TH + 6)
#define LW 536             // bf16 per LDS row (512 + halo/pad; stride 1072B)
#define CPR4 134           // float4 chunks per row (LW/4)
#define NCHK (IH*CPR4)     // 2948 chunks

typedef __attribute__((ext_vector_type(8))) short bf16x8;
typedef __attribute__((ext_vector_type(4))) float f32x4;

__device__ __forceinline__ unsigned short f2bf(float f) {
    union { float f; unsigned u; } v; v.f = f;
    unsigned r = v.u + 0x7FFFu + ((v.u >> 16) & 1u);   // RNE
    return (unsigned short)(r >> 16);
}

__global__ __launch_bounds__(256, 6) void conv7x7(
    const float* __restrict__ x, const float* __restrict__ wgt,
    const float* __restrict__ bias, float* __restrict__ out)
{
    __shared__ unsigned short tile[IH * LW];   // 23,584 B -> 6 blocks/CU
    __shared__ float wlds[49];

    const int tid = threadIdx.x;
    const int x0  = blockIdx.x * 512;          // aligned 512-wide stripes
    const int y0  = blockIdx.y * TH;

    if (tid < 49) wlds[tid] = wgt[tid];
    const float bb = bias[0];

    // ---- stage: ALL 12 loads issued first (in-flight together), then cvt ----
    float4 qv[12];
    int   crow[12], ccol[12];
    #pragma unroll
    for (int k = 0; k < 12; ++k) {
        const int c = tid + (k << 8);
        const int row = c / CPR4;              // magic-mul div
        const int c4  = c - row * CPR4;
        const int rowc = (c < NCHK) ? row : (IH - 1);
        int gy  = y0 + rowc;      gy  = gy  < HI ? gy : HI - 1;
        int gxs = x0 + (c4 << 2); gxs = gxs <= WI - 4 ? gxs : WI - 4;
        crow[k] = rowc; ccol[k] = (c4 << 2);
        qv[k] = *(const float4*)(x + (size_t)gy * WI + gxs);
    }
    #pragma unroll
    for (int k = 0; k < 12; ++k) {
        const int c = tid + (k << 8);
        if (c < NCHK) {
            unsigned u0 = (unsigned)f2bf(qv[k].x) | ((unsigned)f2bf(qv[k].y) << 16);
            unsigned u1 = (unsigned)f2bf(qv[k].z) | ((unsigned)f2bf(qv[k].w) << 16);
            *(uint2*)&tile[crow[k] * LW + ccol[k]] = make_uint2(u0, u1);
        }
    }
    __syncthreads();

    // ---- per-lane banded B fragments: B_ky[k][n] = W[ky][k-n], 0<=k-n<7 ----
    const int n   = tid & 15;                // B col / D col (lane&15)
    const int kb8 = ((tid >> 4) & 3) << 3;   // k-block base (lane>>4)*8
    bf16x8 Bf[7];
    #pragma unroll
    for (int ky = 0; ky < 7; ++ky) {
        #pragma unroll
        for (int j = 0; j < 8; ++j) {
            const int t = kb8 + j - n;                     // tap index
            const float wv = (t >= 0 && t < 7) ? wlds[ky * 7 + t] : 0.f;
            Bf[ky][j] = (short)f2bf(wv);
        }
    }

    // ---- compute: 8 x-tiles per wave, pairs for ILP; 7 MFMA per tile ----
    const int wcol  = (tid >> 6) << 7;       // wave col base 0/128/256/384
    const int growb = y0 + (((tid >> 4) & 3) << 2);   // D row base

    #pragma unroll
    for (int tp = 0; tp < 4; ++tp) {
        const int xt0 = wcol + (tp << 5);
        const int xt1 = xt0 + 16;
        f32x4 acc0 = {0.f, 0.f, 0.f, 0.f};
        f32x4 acc1 = {0.f, 0.f, 0.f, 0.f};
        #pragma unroll
        for (int ky = 0; ky < 7; ++ky) {
            const unsigned short* rp = &tile[(ky + n) * LW + kb8];
            const bf16x8 av0 = *(const bf16x8*)(rp + xt0);   // 16B aligned
            const bf16x8 av1 = *(const bf16x8*)(rp + xt1);
            acc0 = __builtin_amdgcn_mfma_f32_16x16x32_bf16(av0, Bf[ky], acc0, 0, 0, 0);
            acc1 = __builtin_amdgcn_mfma_f32_16x16x32_bf16(av1, Bf[ky], acc1, 0, 0, 0);
        }
        const int gc0 = x0 + xt0 + n;
        const int gc1 = gc0 + 16;
        #pragma unroll
        for (int v = 0; v < 4; ++v) {
            const int grow = growb + v;
            if (grow < HO) {
                if (gc0 < WO) out[(size_t)grow * WO + gc0] = acc0[v] + bb;
                if (gc1 < WO) out[(size_t)grow * WO + gc1] = acc1[v] + bb;
            }
        }
    }
}

extern "C" void kernel_launch(void* const* d_in, const int* in_sizes, int n_in,
                              void* d_out, int out_size, void* d_ws, size_t ws_size,
                              hipStream_t stream) {
    const float* x = (const float*)d_in[0];
    const float* w = (const float*)d_in[1];
    const float* b = (const float*)d_in[2];
    float* out = (float*)d_out;
    // x: 8 stripes x 512 cols; y: ceil(4090/16) = 256 segments
    dim3 grid(8, 256);
    conv7x7<<<grid, 256, 0, stream>>>(x, w, b, out);
}